// Round 1
// baseline (877.942 us; speedup 1.0000x reference)
//
#include <hip/hip_runtime.h>

#define DIM 128
#define BN_EPS 1e-5f

// ---------------- degree / norm ----------------

__global__ void deg_kernel(const int* __restrict__ row, int* __restrict__ deg, int E) {
    int e = blockIdx.x * blockDim.x + threadIdx.x;
    if (e < E) atomicAdd(&deg[row[e]], 1);
}

__global__ void dis_kernel(const int* __restrict__ deg, float* __restrict__ dis, int n) {
    int i = blockIdx.x * blockDim.x + threadIdx.x;
    if (i < n) dis[i] = rsqrtf((float)(deg[i] + 1));  // +1 self-loop; always > 0
}

// ---------------- GEMM: C[n,128] = A'[n,128] @ W[128,128] ----------------
// A' = A (BN=false) or relu(gamma*(A-mean)*istd+beta) (BN=true, per-column k).
// Block: 256 threads = 16 (tx: col groups of 8) x 16 (ty: row groups of 4).
// Tile: 64 rows. A staged in LDS (pad +4 -> 2-way bank aliasing, free).
// W streamed from global: 64 KB, L1/L2-resident, 16-way broadcast across ty.

template <bool BN>
__global__ __launch_bounds__(256) void gemm_kernel(
    const float* __restrict__ A, const float* __restrict__ W,
    float* __restrict__ C, int n,
    const float* __restrict__ mean, const float* __restrict__ istd,
    const float* __restrict__ gamma, const float* __restrict__ beta)
{
    __shared__ float sA[64][DIM + 4];
    const int tid = threadIdx.x;
    const int tx = tid & 15;       // column group: cols tx*8 .. tx*8+7
    const int ty = tid >> 4;       // row group: rows ty*4 .. ty*4+3
    const int row0 = blockIdx.x * 64;

    // Stage A tile: 64x128 floats = 2048 float4, 8 per thread.
    #pragma unroll
    for (int l = 0; l < 8; ++l) {
        int idx = tid + l * 256;          // float4 index in tile
        int r   = idx >> 5;               // 32 float4 per row
        int c4  = (idx & 31) * 4;
        float4 v;
        if (row0 + r < n) v = *(const float4*)(A + (size_t)(row0 + r) * DIM + c4);
        else              v = make_float4(0.f, 0.f, 0.f, 0.f);
        if (BN) {
            float4 m = *(const float4*)(mean  + c4);
            float4 s = *(const float4*)(istd  + c4);
            float4 g = *(const float4*)(gamma + c4);
            float4 b = *(const float4*)(beta  + c4);
            v.x = fmaxf(fmaf(g.x * (v.x - m.x), s.x, b.x), 0.f);
            v.y = fmaxf(fmaf(g.y * (v.y - m.y), s.y, b.y), 0.f);
            v.z = fmaxf(fmaf(g.z * (v.z - m.z), s.z, b.z), 0.f);
            v.w = fmaxf(fmaf(g.w * (v.w - m.w), s.w, b.w), 0.f);
        }
        *(float4*)(&sA[r][c4]) = v;
    }
    __syncthreads();

    float acc[4][8];
    #pragma unroll
    for (int r = 0; r < 4; ++r)
        #pragma unroll
        for (int c = 0; c < 8; ++c) acc[r][c] = 0.f;

    const float* wk = W + tx * 8;
    #pragma unroll 4
    for (int k = 0; k < DIM; ++k) {
        const float a0 = sA[(ty << 2) + 0][k];
        const float a1 = sA[(ty << 2) + 1][k];
        const float a2 = sA[(ty << 2) + 2][k];
        const float a3 = sA[(ty << 2) + 3][k];
        const float4 w0 = *(const float4*)(wk + k * DIM);
        const float4 w1 = *(const float4*)(wk + k * DIM + 4);
        const float wv[8] = {w0.x, w0.y, w0.z, w0.w, w1.x, w1.y, w1.z, w1.w};
        #pragma unroll
        for (int c = 0; c < 8; ++c) {
            acc[0][c] = fmaf(a0, wv[c], acc[0][c]);
            acc[1][c] = fmaf(a1, wv[c], acc[1][c]);
            acc[2][c] = fmaf(a2, wv[c], acc[2][c]);
            acc[3][c] = fmaf(a3, wv[c], acc[3][c]);
        }
    }

    #pragma unroll
    for (int r = 0; r < 4; ++r) {
        int rr = row0 + (ty << 2) + r;
        if (rr < n) {
            float4 o0 = make_float4(acc[r][0], acc[r][1], acc[r][2], acc[r][3]);
            float4 o1 = make_float4(acc[r][4], acc[r][5], acc[r][6], acc[r][7]);
            *(float4*)(C + (size_t)rr * DIM + tx * 8)     = o0;
            *(float4*)(C + (size_t)rr * DIM + tx * 8 + 4) = o1;
        }
    }
}

// ---------------- edge aggregation: out[row] += hw[col] * dis[row]*dis[col] ----------------
// 1 thread per (edge, channel). Coalesced gather + coalesced fp32 atomics.

__global__ void edge_agg_kernel(const float* __restrict__ hw, const float* __restrict__ dis,
                                const int* __restrict__ row, const int* __restrict__ col,
                                float* __restrict__ out, int E)
{
    int gid = blockIdx.x * blockDim.x + threadIdx.x;   // E*128 = 76.8M < 2^31
    if (gid >= E * DIM) return;
    int e = gid >> 7;
    int j = gid & (DIM - 1);
    int r = row[e], c = col[e];
    float nrm = dis[r] * dis[c];
    atomicAdd(&out[(size_t)r * DIM + j], hw[(size_t)c * DIM + j] * nrm);
}

// ---------------- self-loop + bias (+ BN column stats) ----------------
// h[i][j] = agg[i][j] + hw[i][j]*dis[i]^2 + bias[j]; column sum/sumsq -> stat[256].

__global__ __launch_bounds__(256) void self_bias_stats_kernel(
    const float* __restrict__ hw, const float* __restrict__ dis,
    const float* __restrict__ bias, float* __restrict__ h,
    float* __restrict__ stat, int n)
{
    const int tid = threadIdx.x;
    const int j = tid & (DIM - 1);
    const int ty = tid >> 7;           // 0 or 1
    const float bj = bias[j];
    float s = 0.f, s2 = 0.f;
    for (int i = blockIdx.x * 2 + ty; i < n; i += gridDim.x * 2) {
        const float d = dis[i];
        const size_t off = (size_t)i * DIM + j;
        const float v = h[off] + hw[off] * d * d + bj;
        h[off] = v;
        s += v;
        s2 += v * v;
    }
    __shared__ float ls[256], ls2[256];
    ls[tid] = s; ls2[tid] = s2;
    __syncthreads();
    if (tid < DIM) {
        atomicAdd(&stat[j],       ls[tid] + ls[tid + DIM]);
        atomicAdd(&stat[DIM + j], ls2[tid] + ls2[tid + DIM]);
    }
}

__global__ void bn_finalize_kernel(const float* __restrict__ stat, float* __restrict__ mi, int n) {
    int j = threadIdx.x;
    if (j < DIM) {
        float mean = stat[j] / (float)n;
        float var  = stat[DIM + j] / (float)n - mean * mean;
        mi[j]       = mean;
        mi[DIM + j] = rsqrtf(var + BN_EPS);
    }
}

__global__ void self_bias_out_kernel(const float* __restrict__ hw, const float* __restrict__ dis,
                                     const float* __restrict__ bias, float* __restrict__ out, int n)
{
    int gid = blockIdx.x * blockDim.x + threadIdx.x;
    if (gid >= n * DIM) return;
    int i = gid >> 7;
    int j = gid & (DIM - 1);
    float d = dis[i];
    out[gid] += hw[gid] * d * d + bias[j];
}

// ---------------- launch ----------------

extern "C" void kernel_launch(void* const* d_in, const int* in_sizes, int n_in,
                              void* d_out, int out_size, void* d_ws, size_t ws_size,
                              hipStream_t stream)
{
    const float* x      = (const float*)d_in[0];
    const int*   ei     = (const int*)  d_in[1];
    const float* W1     = (const float*)d_in[2];
    const float* b1     = (const float*)d_in[3];
    const float* gamma1 = (const float*)d_in[4];
    const float* beta1  = (const float*)d_in[5];
    const float* W2     = (const float*)d_in[6];
    const float* b2     = (const float*)d_in[7];
    float* out = (float*)d_out;

    const int N = in_sizes[0] / DIM;   // 100000
    const int E = in_sizes[1] / 2;     // 600000
    const int* row = ei;
    const int* col = ei + E;

    // Workspace layout (~52 MB): hw[N*128] | dis[N] | deg[N] | stat[256] | mi[256]
    float* hw   = (float*)d_ws;
    float* dis  = hw + (size_t)N * DIM;
    int*   deg  = (int*)(dis + N);
    float* stat = (float*)(deg + N);
    float* mi   = stat + 256;
    // Layer-1 aggregate lives in d_out (scratch until the final aggregation).

    hipMemsetAsync(deg,  0, (size_t)N * sizeof(int), stream);
    hipMemsetAsync(stat, 0, 256 * sizeof(float), stream);
    hipMemsetAsync(out,  0, (size_t)N * DIM * sizeof(float), stream);

    deg_kernel<<<(E + 255) / 256, 256, 0, stream>>>(row, deg, E);
    dis_kernel<<<(N + 255) / 256, 256, 0, stream>>>(deg, dis, N);

    // Layer 1: hw = x @ W1 ; aggregate into d_out ; + self-loop + b1 + BN stats
    gemm_kernel<false><<<(N + 63) / 64, 256, 0, stream>>>(x, W1, hw, N,
                                                          nullptr, nullptr, nullptr, nullptr);
    edge_agg_kernel<<<(E * DIM + 255) / 256, 256, 0, stream>>>(hw, dis, row, col, out, E);
    self_bias_stats_kernel<<<512, 256, 0, stream>>>(hw, dis, b1, out, stat, N);
    bn_finalize_kernel<<<1, DIM, 0, stream>>>(stat, mi, N);

    // Layer 2: hw = relu(BN(h1)) @ W2 (BN fused into A load); aggregate into d_out
    gemm_kernel<true><<<(N + 63) / 64, 256, 0, stream>>>(out, W2, hw, N,
                                                         mi, mi + DIM, gamma1, beta1);
    hipMemsetAsync(out, 0, (size_t)N * DIM * sizeof(float), stream);
    edge_agg_kernel<<<(E * DIM + 255) / 256, 256, 0, stream>>>(hw, dis, row, col, out, E);
    self_bias_out_kernel<<<(N * DIM + 255) / 256, 256, 0, stream>>>(hw, dis, b2, out, N);
}

// Round 2
// 480.674 us; speedup vs baseline: 1.8265x; 1.8265x over previous
//
#include <hip/hip_runtime.h>

#define DIM 128
#define BN_EPS 1e-5f

// ---------------- degree / norm ----------------

__global__ void deg_kernel(const int* __restrict__ row, int* __restrict__ deg, int E) {
    int e = blockIdx.x * blockDim.x + threadIdx.x;
    if (e < E) atomicAdd(&deg[row[e]], 1);
}

__global__ void dis_kernel(const int* __restrict__ deg, float* __restrict__ dis, int n) {
    int i = blockIdx.x * blockDim.x + threadIdx.x;
    if (i < n) dis[i] = rsqrtf((float)(deg[i] + 1));  // +1 self-loop; always > 0
}

// ---------------- exclusive scan over deg -> rowptr ----------------
// 1024 elements per 256-thread block; block sums to aux; serial aux scan; add-back.

__global__ __launch_bounds__(256) void scan_block_kernel(const int* __restrict__ deg,
                                                         int* __restrict__ rowptr,
                                                         int* __restrict__ aux, int n) {
    __shared__ int ls[256];
    const int base = blockIdx.x * 1024;
    const int t = threadIdx.x;
    int v[4]; int s = 0;
    #pragma unroll
    for (int k = 0; k < 4; ++k) {
        int i = base + t * 4 + k;
        v[k] = (i < n) ? deg[i] : 0;
        s += v[k];
    }
    ls[t] = s;
    __syncthreads();
    for (int off = 1; off < 256; off <<= 1) {
        int x = (t >= off) ? ls[t - off] : 0;
        __syncthreads();
        ls[t] += x;
        __syncthreads();
    }
    int excl = ls[t] - s;
    if (t == 255) aux[blockIdx.x] = ls[255];
    #pragma unroll
    for (int k = 0; k < 4; ++k) {
        int i = base + t * 4 + k;
        if (i < n) rowptr[i] = excl;
        excl += v[k];
    }
}

__global__ void scan_aux_kernel(int* __restrict__ aux, int nb, int* __restrict__ rowptr, int n, int E) {
    int s = 0;
    for (int i = 0; i < nb; ++i) { int v = aux[i]; aux[i] = s; s += v; }
    rowptr[n] = E;
}

__global__ void add_offsets_kernel(int* __restrict__ rowptr, const int* __restrict__ aux, int n) {
    int i = blockIdx.x * blockDim.x + threadIdx.x;
    if (i < n) rowptr[i] += aux[i >> 10];
}

// ---------------- scatter edges into CSR buckets (order within row irrelevant) ----

__global__ void scatter_kernel(const int* __restrict__ row, const int* __restrict__ col,
                               const float* __restrict__ dis, const int* __restrict__ rowptr,
                               int* __restrict__ cursor, int* __restrict__ ecol,
                               float* __restrict__ enorm, int E) {
    int e = blockIdx.x * blockDim.x + threadIdx.x;
    if (e >= E) return;
    int r = row[e], c = col[e];
    int pos = rowptr[r] + atomicAdd(&cursor[r], 1);
    ecol[pos]  = c;
    enorm[pos] = dis[r] * dis[c];
}

// ---------------- GEMM: C[n,128] = A'[n,128] @ W[128,128] ----------------

template <bool BN>
__global__ __launch_bounds__(256) void gemm_kernel(
    const float* __restrict__ A, const float* __restrict__ W,
    float* __restrict__ C, int n,
    const float* __restrict__ mean, const float* __restrict__ istd,
    const float* __restrict__ gamma, const float* __restrict__ beta)
{
    __shared__ float sA[64][DIM + 4];
    const int tid = threadIdx.x;
    const int tx = tid & 15;       // column group: cols tx*8 .. tx*8+7
    const int ty = tid >> 4;       // row group: rows ty*4 .. ty*4+3
    const int row0 = blockIdx.x * 64;

    #pragma unroll
    for (int l = 0; l < 8; ++l) {
        int idx = tid + l * 256;
        int r   = idx >> 5;
        int c4  = (idx & 31) * 4;
        float4 v;
        if (row0 + r < n) v = *(const float4*)(A + (size_t)(row0 + r) * DIM + c4);
        else              v = make_float4(0.f, 0.f, 0.f, 0.f);
        if (BN) {
            float4 m = *(const float4*)(mean  + c4);
            float4 s = *(const float4*)(istd  + c4);
            float4 g = *(const float4*)(gamma + c4);
            float4 b = *(const float4*)(beta  + c4);
            v.x = fmaxf(fmaf(g.x * (v.x - m.x), s.x, b.x), 0.f);
            v.y = fmaxf(fmaf(g.y * (v.y - m.y), s.y, b.y), 0.f);
            v.z = fmaxf(fmaf(g.z * (v.z - m.z), s.z, b.z), 0.f);
            v.w = fmaxf(fmaf(g.w * (v.w - m.w), s.w, b.w), 0.f);
        }
        *(float4*)(&sA[r][c4]) = v;
    }
    __syncthreads();

    float acc[4][8];
    #pragma unroll
    for (int r = 0; r < 4; ++r)
        #pragma unroll
        for (int c = 0; c < 8; ++c) acc[r][c] = 0.f;

    const float* wk = W + tx * 8;
    #pragma unroll 4
    for (int k = 0; k < DIM; ++k) {
        const float a0 = sA[(ty << 2) + 0][k];
        const float a1 = sA[(ty << 2) + 1][k];
        const float a2 = sA[(ty << 2) + 2][k];
        const float a3 = sA[(ty << 2) + 3][k];
        const float4 w0 = *(const float4*)(wk + k * DIM);
        const float4 w1 = *(const float4*)(wk + k * DIM + 4);
        const float wv[8] = {w0.x, w0.y, w0.z, w0.w, w1.x, w1.y, w1.z, w1.w};
        #pragma unroll
        for (int c = 0; c < 8; ++c) {
            acc[0][c] = fmaf(a0, wv[c], acc[0][c]);
            acc[1][c] = fmaf(a1, wv[c], acc[1][c]);
            acc[2][c] = fmaf(a2, wv[c], acc[2][c]);
            acc[3][c] = fmaf(a3, wv[c], acc[3][c]);
        }
    }

    #pragma unroll
    for (int r = 0; r < 4; ++r) {
        int rr = row0 + (ty << 2) + r;
        if (rr < n) {
            float4 o0 = make_float4(acc[r][0], acc[r][1], acc[r][2], acc[r][3]);
            float4 o1 = make_float4(acc[r][4], acc[r][5], acc[r][6], acc[r][7]);
            *(float4*)(C + (size_t)rr * DIM + tx * 8)     = o0;
            *(float4*)(C + (size_t)rr * DIM + tx * 8 + 4) = o1;
        }
    }
}

// ---------------- CSR aggregation: out[i] = sum_e hw[col_e]*norm_e + hw[i]*dis_i^2 + bias ----
// One 64-lane wave per node; lane holds channels 2*lane, 2*lane+1 (float2).
// Gathers are 512 B contiguous per edge, coalesced across the wave. No atomics.

__global__ __launch_bounds__(256) void agg_csr_kernel(
    const float* __restrict__ hw, const float* __restrict__ dis,
    const int* __restrict__ rowptr, const int* __restrict__ ecol,
    const float* __restrict__ enorm, const float* __restrict__ bias,
    float* __restrict__ out, int n)
{
    const int wid  = threadIdx.x >> 6;
    const int lane = threadIdx.x & 63;
    const int node = blockIdx.x * 4 + wid;
    if (node >= n) return;
    const int j = lane * 2;

    const float d = dis[node];
    float2 sv = *(const float2*)(hw + (size_t)node * DIM + j);
    float accx = sv.x * d * d;
    float accy = sv.y * d * d;

    int p  = rowptr[node];
    const int pe = rowptr[node + 1];
    for (; p + 1 < pe; p += 2) {
        int   c0 = ecol[p],     c1 = ecol[p + 1];
        float w0 = enorm[p],    w1 = enorm[p + 1];
        float2 v0 = *(const float2*)(hw + (size_t)c0 * DIM + j);
        float2 v1 = *(const float2*)(hw + (size_t)c1 * DIM + j);
        accx = fmaf(v0.x, w0, accx);
        accy = fmaf(v0.y, w0, accy);
        accx = fmaf(v1.x, w1, accx);
        accy = fmaf(v1.y, w1, accy);
    }
    if (p < pe) {
        int c = ecol[p];
        float w = enorm[p];
        float2 v = *(const float2*)(hw + (size_t)c * DIM + j);
        accx = fmaf(v.x, w, accx);
        accy = fmaf(v.y, w, accy);
    }

    float2 b = *(const float2*)(bias + j);
    float2 o;
    o.x = accx + b.x;
    o.y = accy + b.y;
    *(float2*)(out + (size_t)node * DIM + j) = o;
}

// ---------------- BN column stats (read-only) ----------------

__global__ __launch_bounds__(256) void stats_kernel(const float* __restrict__ h,
                                                    float* __restrict__ stat, int n)
{
    const int tid = threadIdx.x;
    const int j = tid & (DIM - 1);
    const int ty = tid >> 7;
    float s = 0.f, s2 = 0.f;
    for (int i = blockIdx.x * 2 + ty; i < n; i += gridDim.x * 2) {
        const float v = h[(size_t)i * DIM + j];
        s += v;
        s2 += v * v;
    }
    __shared__ float ls[256], ls2[256];
    ls[tid] = s; ls2[tid] = s2;
    __syncthreads();
    if (tid < DIM) {
        atomicAdd(&stat[j],       ls[tid] + ls[tid + DIM]);
        atomicAdd(&stat[DIM + j], ls2[tid] + ls2[tid + DIM]);
    }
}

__global__ void bn_finalize_kernel(const float* __restrict__ stat, float* __restrict__ mi, int n) {
    int j = threadIdx.x;
    if (j < DIM) {
        float mean = stat[j] / (float)n;
        float var  = stat[DIM + j] / (float)n - mean * mean;
        mi[j]       = mean;
        mi[DIM + j] = rsqrtf(var + BN_EPS);
    }
}

// ---------------- launch ----------------

extern "C" void kernel_launch(void* const* d_in, const int* in_sizes, int n_in,
                              void* d_out, int out_size, void* d_ws, size_t ws_size,
                              hipStream_t stream)
{
    const float* x      = (const float*)d_in[0];
    const int*   ei     = (const int*)  d_in[1];
    const float* W1     = (const float*)d_in[2];
    const float* b1     = (const float*)d_in[3];
    const float* gamma1 = (const float*)d_in[4];
    const float* beta1  = (const float*)d_in[5];
    const float* W2     = (const float*)d_in[6];
    const float* b2     = (const float*)d_in[7];
    float* out = (float*)d_out;

    const int N = in_sizes[0] / DIM;   // 100000
    const int E = in_sizes[1] / 2;     // 600000
    const int* row = ei;
    const int* col = ei + E;

    const int NB = (N + 1023) / 1024;  // scan blocks (98)

    // Workspace layout (~58 MB):
    float* hw     = (float*)d_ws;                 // N*128 floats
    float* dis    = hw + (size_t)N * DIM;         // N
    int*   deg    = (int*)(dis + N);              // N
    int*   cursor = deg + N;                      // N
    int*   rowptr = cursor + N;                   // N+1
    int*   aux    = rowptr + N + 1;               // 128
    float* stat   = (float*)(aux + 128);          // 256
    float* mi     = stat + 256;                   // 256
    int*   ecol   = (int*)(mi + 256);             // E
    float* enorm  = (float*)(ecol + E);           // E
    // Layer-1 hidden h1 lives in d_out (scratch until the final aggregation).

    hipMemsetAsync(deg,    0, (size_t)N * sizeof(int), stream);
    hipMemsetAsync(cursor, 0, (size_t)N * sizeof(int), stream);
    hipMemsetAsync(stat,   0, 256 * sizeof(float), stream);

    // Graph structure: degree -> dis -> rowptr (scan) -> CSR scatter
    deg_kernel<<<(E + 255) / 256, 256, 0, stream>>>(row, deg, E);
    dis_kernel<<<(N + 255) / 256, 256, 0, stream>>>(deg, dis, N);
    scan_block_kernel<<<NB, 256, 0, stream>>>(deg, rowptr, aux, N);
    scan_aux_kernel<<<1, 1, 0, stream>>>(aux, NB, rowptr, N, E);
    add_offsets_kernel<<<(N + 255) / 256, 256, 0, stream>>>(rowptr, aux, N);
    scatter_kernel<<<(E + 255) / 256, 256, 0, stream>>>(row, col, dis, rowptr, cursor,
                                                        ecol, enorm, E);

    // Layer 1: hw = x @ W1 ; h1 = agg(hw) + self + b1 (into d_out) ; BN stats
    gemm_kernel<false><<<(N + 63) / 64, 256, 0, stream>>>(x, W1, hw, N,
                                                          nullptr, nullptr, nullptr, nullptr);
    agg_csr_kernel<<<(N + 3) / 4, 256, 0, stream>>>(hw, dis, rowptr, ecol, enorm, b1, out, N);
    stats_kernel<<<512, 256, 0, stream>>>(out, stat, N);
    bn_finalize_kernel<<<1, DIM, 0, stream>>>(stat, mi, N);

    // Layer 2: hw = relu(BN(h1)) @ W2 (BN fused into A load); out = agg(hw) + self + b2
    gemm_kernel<true><<<(N + 63) / 64, 256, 0, stream>>>(out, W2, hw, N,
                                                         mi, mi + DIM, gamma1, beta1);
    agg_csr_kernel<<<(N + 3) / 4, 256, 0, stream>>>(hw, dis, rowptr, ecol, enorm, b2, out, N);
}

// Round 3
// 373.454 us; speedup vs baseline: 2.3509x; 1.2871x over previous
//
#include <hip/hip_runtime.h>

#define DIM 128
#define BN_EPS 1e-5f

typedef short short8 __attribute__((ext_vector_type(8)));   // 8 bf16 bit patterns
typedef float floatx4 __attribute__((ext_vector_type(4)));

__device__ __forceinline__ unsigned short f2bf(float f) {
    unsigned int u = __builtin_bit_cast(unsigned int, f);
    u += 0x7FFFu + ((u >> 16) & 1u);          // RNE (inputs are finite)
    return (unsigned short)(u >> 16);
}
__device__ __forceinline__ float bf2f(unsigned short h) {
    return __builtin_bit_cast(float, (unsigned int)h << 16);
}

// ---------------- degree / norm ----------------

__global__ void deg_kernel(const int* __restrict__ row, int* __restrict__ deg, int E) {
    int e = blockIdx.x * blockDim.x + threadIdx.x;
    if (e < E) atomicAdd(&deg[row[e]], 1);
}

__global__ void dis_kernel(const int* __restrict__ deg, float* __restrict__ dis, int n) {
    int i = blockIdx.x * blockDim.x + threadIdx.x;
    if (i < n) dis[i] = rsqrtf((float)(deg[i] + 1));  // +1 self-loop; always > 0
}

// ---------------- exclusive scan over deg -> rowptr ----------------

__global__ __launch_bounds__(256) void scan_block_kernel(const int* __restrict__ deg,
                                                         int* __restrict__ rowptr,
                                                         int* __restrict__ aux, int n) {
    __shared__ int ls[256];
    const int base = blockIdx.x * 1024;
    const int t = threadIdx.x;
    int v[4]; int s = 0;
    #pragma unroll
    for (int k = 0; k < 4; ++k) {
        int i = base + t * 4 + k;
        v[k] = (i < n) ? deg[i] : 0;
        s += v[k];
    }
    ls[t] = s;
    __syncthreads();
    for (int off = 1; off < 256; off <<= 1) {
        int x = (t >= off) ? ls[t - off] : 0;
        __syncthreads();
        ls[t] += x;
        __syncthreads();
    }
    int excl = ls[t] - s;
    if (t == 255) aux[blockIdx.x] = ls[255];
    #pragma unroll
    for (int k = 0; k < 4; ++k) {
        int i = base + t * 4 + k;
        if (i < n) rowptr[i] = excl;
        excl += v[k];
    }
}

__global__ void scan_aux_kernel(int* __restrict__ aux, int nb, int* __restrict__ rowptr, int n, int E) {
    int s = 0;
    for (int i = 0; i < nb; ++i) { int v = aux[i]; aux[i] = s; s += v; }
    rowptr[n] = E;
}

__global__ void add_offsets_kernel(int* __restrict__ rowptr, const int* __restrict__ aux, int n) {
    int i = blockIdx.x * blockDim.x + threadIdx.x;
    if (i < n) rowptr[i] += aux[i >> 10];
}

// ---------------- scatter edges into CSR buckets ----------------

__global__ void scatter_kernel(const int* __restrict__ row, const int* __restrict__ col,
                               const float* __restrict__ dis, const int* __restrict__ rowptr,
                               int* __restrict__ cursor, int* __restrict__ ecol,
                               float* __restrict__ enorm, int E) {
    int e = blockIdx.x * blockDim.x + threadIdx.x;
    if (e >= E) return;
    int r = row[e], c = col[e];
    int pos = rowptr[r] + atomicAdd(&cursor[r], 1);
    ecol[pos]  = c;
    enorm[pos] = dis[r] * dis[c];
}

// ---------------- W -> bf16 B-fragment order ----------------
// frag layout for mfma_f32_16x16x32_bf16: wfrag[((kt*8+nt)*64 + lane)*8 + j]
//   = W[kt*32 + (lane>>4)*8 + j][nt*16 + (lane&15)]
// => per-(kt,nt) b-frag is one coalesced 16B/lane load. 2 matrices, 2048 slots each.

__global__ void convert_w_kernel(const float* __restrict__ W1, const float* __restrict__ W2,
                                 unsigned short* __restrict__ wfrag) {
    int s = blockIdx.x * blockDim.x + threadIdx.x;   // 0..4095
    if (s >= 4096) return;
    int m  = s >> 11;
    int s2 = s & 2047;
    int kt = s2 >> 9;
    int nt = (s2 >> 6) & 7;
    int l  = s2 & 63;
    const float* W = m ? W2 : W1;
    unsigned short* o = wfrag + (size_t)m * 16384 + (size_t)s2 * 8;
    int k0 = kt * 32 + (l >> 4) * 8;
    int n0 = nt * 16 + (l & 15);
    #pragma unroll
    for (int j = 0; j < 8; ++j) o[j] = f2bf(W[(k0 + j) * DIM + n0]);
}

// ---------------- MFMA GEMM: C[n,128](bf16) = A'[n,128](fp32) @ W(bf16 frags) ----------------
// Block: 256 threads = 4 waves; 64 rows/block, wave w -> rows w*16..w*16+15.
// A staged fp32->bf16 in LDS, pitch 136 (rows 16B-aligned, 2-way bank alias = free).
// b-frags read straight from global wfrag (32 KB, L1-resident).

template <bool BN>
__global__ __launch_bounds__(256) void gemm_mfma_kernel(
    const float* __restrict__ A, const unsigned short* __restrict__ wfrag,
    unsigned short* __restrict__ C, int n,
    const float* __restrict__ mean, const float* __restrict__ istd,
    const float* __restrict__ gamma, const float* __restrict__ beta)
{
    __shared__ unsigned short sA[64][136];
    const int tid  = threadIdx.x;
    const int row0 = blockIdx.x * 64;

    // Stage A tile: 2048 float4 loads -> bf16x4 stores (8 B)
    #pragma unroll
    for (int l = 0; l < 8; ++l) {
        int idx = tid + l * 256;
        int r   = idx >> 5;
        int c4  = (idx & 31) * 4;
        float4 v;
        if (row0 + r < n) v = *(const float4*)(A + (size_t)(row0 + r) * DIM + c4);
        else              v = make_float4(0.f, 0.f, 0.f, 0.f);
        if (BN) {
            float4 m = *(const float4*)(mean  + c4);
            float4 s = *(const float4*)(istd  + c4);
            float4 g = *(const float4*)(gamma + c4);
            float4 b = *(const float4*)(beta  + c4);
            v.x = fmaxf(fmaf(g.x * (v.x - m.x), s.x, b.x), 0.f);
            v.y = fmaxf(fmaf(g.y * (v.y - m.y), s.y, b.y), 0.f);
            v.z = fmaxf(fmaf(g.z * (v.z - m.z), s.z, b.z), 0.f);
            v.w = fmaxf(fmaf(g.w * (v.w - m.w), s.w, b.w), 0.f);
        }
        unsigned int lo = (unsigned int)f2bf(v.x) | ((unsigned int)f2bf(v.y) << 16);
        unsigned int hi = (unsigned int)f2bf(v.z) | ((unsigned int)f2bf(v.w) << 16);
        *(uint2*)(&sA[r][c4]) = make_uint2(lo, hi);
    }
    __syncthreads();

    const int wave = tid >> 6;
    const int lane = tid & 63;
    const int m    = lane & 15;
    const int quad = lane >> 4;
    const int rowA = wave * 16 + m;

    // A-fragments: A[m=lane&15][k = kt*32 + quad*8 + j], contiguous 16 B
    short8 af[4];
    #pragma unroll
    for (int kt = 0; kt < 4; ++kt)
        af[kt] = *(const short8*)(&sA[rowA][kt * 32 + quad * 8]);

    floatx4 acc[8];
    #pragma unroll
    for (int nt = 0; nt < 8; ++nt) acc[nt] = (floatx4){0.f, 0.f, 0.f, 0.f};

    #pragma unroll
    for (int nt = 0; nt < 8; ++nt) {
        #pragma unroll
        for (int kt = 0; kt < 4; ++kt) {
            short8 bfr = *(const short8*)(wfrag + ((size_t)(kt * 8 + nt) * 64 + lane) * 8);
            acc[nt] = __builtin_amdgcn_mfma_f32_16x16x32_bf16(af[kt], bfr, acc[nt], 0, 0, 0);
        }
    }

    // C/D: row = quad*4 + reg, col = lane&15 (within the wave's 16x16 tile)
    #pragma unroll
    for (int nt = 0; nt < 8; ++nt) {
        #pragma unroll
        for (int r = 0; r < 4; ++r) {
            int rr = row0 + wave * 16 + quad * 4 + r;
            if (rr < n) C[(size_t)rr * DIM + nt * 16 + m] = f2bf(acc[nt][r]);
        }
    }
}

// ---------------- CSR aggregation (bf16 messages): ----------------
// out[i] = sum_e hw[col_e]*norm_e + hw[i]*dis_i^2 + bias   (fp32 accumulate/out)

__global__ __launch_bounds__(256) void agg_csr_kernel(
    const unsigned short* __restrict__ hw, const float* __restrict__ dis,
    const int* __restrict__ rowptr, const int* __restrict__ ecol,
    const float* __restrict__ enorm, const float* __restrict__ bias,
    float* __restrict__ out, int n)
{
    const int wid  = threadIdx.x >> 6;
    const int lane = threadIdx.x & 63;
    const int node = blockIdx.x * 4 + wid;
    if (node >= n) return;
    const int j = lane * 2;

    const float d = dis[node];
    ushort2 sv = *(const ushort2*)(hw + (size_t)node * DIM + j);
    float accx = bf2f(sv.x) * d * d;
    float accy = bf2f(sv.y) * d * d;

    int p  = rowptr[node];
    const int pe = rowptr[node + 1];
    for (; p + 1 < pe; p += 2) {
        int   c0 = ecol[p],  c1 = ecol[p + 1];
        float w0 = enorm[p], w1 = enorm[p + 1];
        ushort2 v0 = *(const ushort2*)(hw + (size_t)c0 * DIM + j);
        ushort2 v1 = *(const ushort2*)(hw + (size_t)c1 * DIM + j);
        accx = fmaf(bf2f(v0.x), w0, accx);
        accy = fmaf(bf2f(v0.y), w0, accy);
        accx = fmaf(bf2f(v1.x), w1, accx);
        accy = fmaf(bf2f(v1.y), w1, accy);
    }
    if (p < pe) {
        int c = ecol[p];
        float w = enorm[p];
        ushort2 v = *(const ushort2*)(hw + (size_t)c * DIM + j);
        accx = fmaf(bf2f(v.x), w, accx);
        accy = fmaf(bf2f(v.y), w, accy);
    }

    float2 b = *(const float2*)(bias + j);
    float2 o;
    o.x = accx + b.x;
    o.y = accy + b.y;
    *(float2*)(out + (size_t)node * DIM + j) = o;
}

// ---------------- BN column stats ----------------

__global__ __launch_bounds__(256) void stats_kernel(const float* __restrict__ h,
                                                    float* __restrict__ stat, int n)
{
    const int tid = threadIdx.x;
    const int j = tid & (DIM - 1);
    const int ty = tid >> 7;
    float s = 0.f, s2 = 0.f;
    for (int i = blockIdx.x * 2 + ty; i < n; i += gridDim.x * 2) {
        const float v = h[(size_t)i * DIM + j];
        s += v;
        s2 += v * v;
    }
    __shared__ float ls[256], ls2[256];
    ls[tid] = s; ls2[tid] = s2;
    __syncthreads();
    if (tid < DIM) {
        atomicAdd(&stat[j],       ls[tid] + ls[tid + DIM]);
        atomicAdd(&stat[DIM + j], ls2[tid] + ls2[tid + DIM]);
    }
}

__global__ void bn_finalize_kernel(const float* __restrict__ stat, float* __restrict__ mi, int n) {
    int j = threadIdx.x;
    if (j < DIM) {
        float mean = stat[j] / (float)n;
        float var  = stat[DIM + j] / (float)n - mean * mean;
        mi[j]       = mean;
        mi[DIM + j] = rsqrtf(var + BN_EPS);
    }
}

// ---------------- launch ----------------

extern "C" void kernel_launch(void* const* d_in, const int* in_sizes, int n_in,
                              void* d_out, int out_size, void* d_ws, size_t ws_size,
                              hipStream_t stream)
{
    const float* x      = (const float*)d_in[0];
    const int*   ei     = (const int*)  d_in[1];
    const float* W1     = (const float*)d_in[2];
    const float* b1     = (const float*)d_in[3];
    const float* gamma1 = (const float*)d_in[4];
    const float* beta1  = (const float*)d_in[5];
    const float* W2     = (const float*)d_in[6];
    const float* b2     = (const float*)d_in[7];
    float* out = (float*)d_out;

    const int N = in_sizes[0] / DIM;   // 100000
    const int E = in_sizes[1] / 2;     // 600000
    const int* row = ei;
    const int* col = ei + E;

    const int NB = (N + 1023) / 1024;

    // Workspace layout (~32 MB):
    unsigned short* hw    = (unsigned short*)d_ws;        // N*128 bf16
    unsigned short* wfrag = hw + (size_t)N * DIM;         // 2*16384 bf16
    float* dis    = (float*)(wfrag + 2 * 16384);          // N
    int*   deg    = (int*)(dis + N);                      // N
    int*   cursor = deg + N;                              // N
    int*   rowptr = cursor + N;                           // N+1
    int*   aux    = rowptr + N + 1;                       // 128
    float* stat   = (float*)(aux + 128);                  // 256
    float* mi     = stat + 256;                           // 256
    int*   ecol   = (int*)(mi + 256);                     // E
    float* enorm  = (float*)(ecol + E);                   // E
    // Layer-1 hidden h1 (fp32) lives in d_out until the final aggregation.

    hipMemsetAsync(deg,    0, (size_t)N * sizeof(int), stream);
    hipMemsetAsync(cursor, 0, (size_t)N * sizeof(int), stream);
    hipMemsetAsync(stat,   0, 256 * sizeof(float), stream);

    // Graph structure + W conversion
    deg_kernel<<<(E + 255) / 256, 256, 0, stream>>>(row, deg, E);
    dis_kernel<<<(N + 255) / 256, 256, 0, stream>>>(deg, dis, N);
    scan_block_kernel<<<NB, 256, 0, stream>>>(deg, rowptr, aux, N);
    scan_aux_kernel<<<1, 1, 0, stream>>>(aux, NB, rowptr, N, E);
    add_offsets_kernel<<<(N + 255) / 256, 256, 0, stream>>>(rowptr, aux, N);
    scatter_kernel<<<(E + 255) / 256, 256, 0, stream>>>(row, col, dis, rowptr, cursor,
                                                        ecol, enorm, E);
    convert_w_kernel<<<16, 256, 0, stream>>>(W1, W2, wfrag);

    // Layer 1: hw = bf16(x @ W1) ; h1 = agg(hw)+self+b1 (fp32, in d_out) ; BN stats
    gemm_mfma_kernel<false><<<(N + 63) / 64, 256, 0, stream>>>(x, wfrag, hw, N,
                                                               nullptr, nullptr, nullptr, nullptr);
    agg_csr_kernel<<<(N + 3) / 4, 256, 0, stream>>>(hw, dis, rowptr, ecol, enorm, b1, out, N);
    stats_kernel<<<512, 256, 0, stream>>>(out, stat, N);
    bn_finalize_kernel<<<1, DIM, 0, stream>>>(stat, mi, N);

    // Layer 2: hw = bf16(relu(BN(h1)) @ W2) ; out = agg(hw)+self+b2
    gemm_mfma_kernel<true><<<(N + 63) / 64, 256, 0, stream>>>(out, wfrag + 16384, hw, N,
                                                              mi, mi + DIM, gamma1, beta1);
    agg_csr_kernel<<<(N + 3) / 4, 256, 0, stream>>>(hw, dis, rowptr, ecol, enorm, b2, out, N);
}

// Round 4
// 346.293 us; speedup vs baseline: 2.5353x; 1.0784x over previous
//
#include <hip/hip_runtime.h>

#define DIM 128
#define BN_EPS 1e-5f

typedef short short8 __attribute__((ext_vector_type(8)));   // 8 bf16 bit patterns
typedef float floatx4 __attribute__((ext_vector_type(4)));

__device__ __forceinline__ unsigned short f2bf(float f) {
    unsigned int u = __builtin_bit_cast(unsigned int, f);
    u += 0x7FFFu + ((u >> 16) & 1u);          // RNE (inputs are finite)
    return (unsigned short)(u >> 16);
}
__device__ __forceinline__ float bf2f(unsigned short h) {
    return __builtin_bit_cast(float, (unsigned int)h << 16);
}

// ---------------- degree / norm ----------------

__global__ void deg_kernel(const int* __restrict__ row, int* __restrict__ deg, int E) {
    int e = blockIdx.x * blockDim.x + threadIdx.x;
    if (e < E) atomicAdd(&deg[row[e]], 1);
}

__global__ void dis_kernel(const int* __restrict__ deg, float* __restrict__ dis, int n) {
    int i = blockIdx.x * blockDim.x + threadIdx.x;
    if (i < n) dis[i] = rsqrtf((float)(deg[i] + 1));  // +1 self-loop; always > 0
}

// ---------------- exclusive scan over deg -> rowptr ----------------

__global__ __launch_bounds__(256) void scan_block_kernel(const int* __restrict__ deg,
                                                         int* __restrict__ rowptr,
                                                         int* __restrict__ aux, int n) {
    __shared__ int ls[256];
    const int base = blockIdx.x * 1024;
    const int t = threadIdx.x;
    int v[4]; int s = 0;
    #pragma unroll
    for (int k = 0; k < 4; ++k) {
        int i = base + t * 4 + k;
        v[k] = (i < n) ? deg[i] : 0;
        s += v[k];
    }
    ls[t] = s;
    __syncthreads();
    for (int off = 1; off < 256; off <<= 1) {
        int x = (t >= off) ? ls[t - off] : 0;
        __syncthreads();
        ls[t] += x;
        __syncthreads();
    }
    int excl = ls[t] - s;
    if (t == 255) aux[blockIdx.x] = ls[255];
    #pragma unroll
    for (int k = 0; k < 4; ++k) {
        int i = base + t * 4 + k;
        if (i < n) rowptr[i] = excl;
        excl += v[k];
    }
}

__global__ void scan_aux_kernel(int* __restrict__ aux, int nb, int* __restrict__ rowptr, int n, int E) {
    int s = 0;
    for (int i = 0; i < nb; ++i) { int v = aux[i]; aux[i] = s; s += v; }
    rowptr[n] = E;
}

__global__ void add_offsets_kernel(int* __restrict__ rowptr, const int* __restrict__ aux, int n) {
    int i = blockIdx.x * blockDim.x + threadIdx.x;
    if (i < n) rowptr[i] += aux[i >> 10];
}

// ---------------- scatter edges into CSR buckets: one 8B (col, norm) write ----

__global__ void scatter_kernel(const int* __restrict__ row, const int* __restrict__ col,
                               const float* __restrict__ dis, const int* __restrict__ rowptr,
                               int* __restrict__ cursor, int2* __restrict__ epack, int E) {
    int e = blockIdx.x * blockDim.x + threadIdx.x;
    if (e >= E) return;
    int r = row[e], c = col[e];
    int pos = rowptr[r] + atomicAdd(&cursor[r], 1);
    float nrm = dis[r] * dis[c];
    epack[pos] = make_int2(c, __builtin_bit_cast(int, nrm));
}

// ---------------- W -> bf16 B-fragment order ----------------
// wfrag[((kt*8+nt)*64 + lane)*8 + j] = W[kt*32 + (lane>>4)*8 + j][nt*16 + (lane&15)]

__global__ void convert_w_kernel(const float* __restrict__ W1, const float* __restrict__ W2,
                                 unsigned short* __restrict__ wfrag) {
    int s = blockIdx.x * blockDim.x + threadIdx.x;   // 0..4095
    if (s >= 4096) return;
    int m  = s >> 11;
    int s2 = s & 2047;
    int kt = s2 >> 9;
    int nt = (s2 >> 6) & 7;
    int l  = s2 & 63;
    const float* W = m ? W2 : W1;
    unsigned short* o = wfrag + (size_t)m * 16384 + (size_t)s2 * 8;
    int k0 = kt * 32 + (l >> 4) * 8;
    int n0 = nt * 16 + (l & 15);
    #pragma unroll
    for (int j = 0; j < 8; ++j) o[j] = f2bf(W[(k0 + j) * DIM + n0]);
}

// ---------------- MFMA GEMM, fp32 A input (layer 1, no BN) ----------------
// Block: 4 waves; 64 rows/block, wave w -> rows w*16..w*16+15.
// A staged fp32->bf16 in LDS, pitch 136 (16B-aligned rows, 2-way alias = free).

__global__ __launch_bounds__(256) void gemm_mfma_f32_kernel(
    const float* __restrict__ A, const unsigned short* __restrict__ wfrag,
    unsigned short* __restrict__ C, int n)
{
    __shared__ unsigned short sA[64][136];
    const int tid  = threadIdx.x;
    const int row0 = blockIdx.x * 64;

    #pragma unroll
    for (int l = 0; l < 8; ++l) {
        int idx = tid + l * 256;
        int r   = idx >> 5;
        int c4  = (idx & 31) * 4;
        float4 v;
        if (row0 + r < n) v = *(const float4*)(A + (size_t)(row0 + r) * DIM + c4);
        else              v = make_float4(0.f, 0.f, 0.f, 0.f);
        unsigned int lo = (unsigned int)f2bf(v.x) | ((unsigned int)f2bf(v.y) << 16);
        unsigned int hi = (unsigned int)f2bf(v.z) | ((unsigned int)f2bf(v.w) << 16);
        *(uint2*)(&sA[r][c4]) = make_uint2(lo, hi);
    }
    __syncthreads();

    const int wave = tid >> 6;
    const int lane = tid & 63;
    const int m    = lane & 15;
    const int quad = lane >> 4;
    const int rowA = wave * 16 + m;

    short8 af[4];
    #pragma unroll
    for (int kt = 0; kt < 4; ++kt)
        af[kt] = *(const short8*)(&sA[rowA][kt * 32 + quad * 8]);

    floatx4 acc[8];
    #pragma unroll
    for (int nt = 0; nt < 8; ++nt) acc[nt] = (floatx4){0.f, 0.f, 0.f, 0.f};

    #pragma unroll
    for (int nt = 0; nt < 8; ++nt)
        #pragma unroll
        for (int kt = 0; kt < 4; ++kt) {
            short8 bfr = *(const short8*)(wfrag + ((size_t)(kt * 8 + nt) * 64 + lane) * 8);
            acc[nt] = __builtin_amdgcn_mfma_f32_16x16x32_bf16(af[kt], bfr, acc[nt], 0, 0, 0);
        }

    #pragma unroll
    for (int nt = 0; nt < 8; ++nt)
        #pragma unroll
        for (int r = 0; r < 4; ++r) {
            int rr = row0 + wave * 16 + quad * 4 + r;
            if (rr < n) C[(size_t)rr * DIM + nt * 16 + m] = f2bf(acc[nt][r]);
        }
}

// ---------------- MFMA GEMM, bf16 A input + fused BN/ReLU (layer 2) ----------------

__global__ __launch_bounds__(256) void gemm_mfma_bn_kernel(
    const unsigned short* __restrict__ A, const unsigned short* __restrict__ wfrag,
    unsigned short* __restrict__ C, int n,
    const float* __restrict__ mean, const float* __restrict__ istd,
    const float* __restrict__ gamma, const float* __restrict__ beta)
{
    __shared__ unsigned short sA[64][136];
    const int tid  = threadIdx.x;
    const int row0 = blockIdx.x * 64;

    #pragma unroll
    for (int l = 0; l < 4; ++l) {
        int idx = tid + l * 256;          // 0..1023, 16B chunks
        int r   = idx >> 4;
        int c8  = (idx & 15) * 8;
        uint4 u = make_uint4(0, 0, 0, 0);
        if (row0 + r < n) u = *(const uint4*)(A + (size_t)(row0 + r) * DIM + c8);
        float f[8] = { bf2f((unsigned short)(u.x & 0xffff)), bf2f((unsigned short)(u.x >> 16)),
                       bf2f((unsigned short)(u.y & 0xffff)), bf2f((unsigned short)(u.y >> 16)),
                       bf2f((unsigned short)(u.z & 0xffff)), bf2f((unsigned short)(u.z >> 16)),
                       bf2f((unsigned short)(u.w & 0xffff)), bf2f((unsigned short)(u.w >> 16)) };
        #pragma unroll
        for (int k = 0; k < 8; ++k) {
            int c = c8 + k;
            f[k] = fmaxf(fmaf(gamma[c] * (f[k] - mean[c]), istd[c], beta[c]), 0.f);
        }
        uint4 o;
        o.x = (unsigned int)f2bf(f[0]) | ((unsigned int)f2bf(f[1]) << 16);
        o.y = (unsigned int)f2bf(f[2]) | ((unsigned int)f2bf(f[3]) << 16);
        o.z = (unsigned int)f2bf(f[4]) | ((unsigned int)f2bf(f[5]) << 16);
        o.w = (unsigned int)f2bf(f[6]) | ((unsigned int)f2bf(f[7]) << 16);
        *(uint4*)(&sA[r][c8]) = o;
    }
    __syncthreads();

    const int wave = tid >> 6;
    const int lane = tid & 63;
    const int m    = lane & 15;
    const int quad = lane >> 4;
    const int rowA = wave * 16 + m;

    short8 af[4];
    #pragma unroll
    for (int kt = 0; kt < 4; ++kt)
        af[kt] = *(const short8*)(&sA[rowA][kt * 32 + quad * 8]);

    floatx4 acc[8];
    #pragma unroll
    for (int nt = 0; nt < 8; ++nt) acc[nt] = (floatx4){0.f, 0.f, 0.f, 0.f};

    #pragma unroll
    for (int nt = 0; nt < 8; ++nt)
        #pragma unroll
        for (int kt = 0; kt < 4; ++kt) {
            short8 bfr = *(const short8*)(wfrag + ((size_t)(kt * 8 + nt) * 64 + lane) * 8);
            acc[nt] = __builtin_amdgcn_mfma_f32_16x16x32_bf16(af[kt], bfr, acc[nt], 0, 0, 0);
        }

    #pragma unroll
    for (int nt = 0; nt < 8; ++nt)
        #pragma unroll
        for (int r = 0; r < 4; ++r) {
            int rr = row0 + wave * 16 + quad * 4 + r;
            if (rr < n) C[(size_t)rr * DIM + nt * 16 + m] = f2bf(acc[nt][r]);
        }
}

// ---------------- CSR aggregation: 2 nodes/wave, 32 lanes/node, 4 ch/lane ----------------
// out[i] = sum_e hw[col_e]*norm_e + hw[i]*dis_i^2 + bias ; fp32 accumulate.
// OUT_BF16: write bf16 (layer-1 hidden). Else fp32 (final output).

template <bool OUT_BF16>
__global__ __launch_bounds__(256) void agg_csr_kernel(
    const unsigned short* __restrict__ hw, const float* __restrict__ dis,
    const int* __restrict__ rowptr, const int2* __restrict__ epack,
    const float* __restrict__ bias, void* __restrict__ out_, int n)
{
    const int sub  = threadIdx.x >> 5;        // 0..7 (half-wave id within block)
    const int l    = threadIdx.x & 31;
    const int node = blockIdx.x * 8 + sub;
    if (node >= n) return;
    const int j = l * 4;

    const float d = dis[node];
    const float dd = d * d;
    ushort4 sv = *(const ushort4*)(hw + (size_t)node * DIM + j);
    float a0 = bf2f(sv.x) * dd, a1 = bf2f(sv.y) * dd,
          a2 = bf2f(sv.z) * dd, a3 = bf2f(sv.w) * dd;

    int p  = rowptr[node];
    const int pe = rowptr[node + 1];
    for (; p + 1 < pe; p += 2) {
        int2 e0 = epack[p], e1 = epack[p + 1];
        float w0 = __builtin_bit_cast(float, e0.y);
        float w1 = __builtin_bit_cast(float, e1.y);
        ushort4 v0 = *(const ushort4*)(hw + (size_t)e0.x * DIM + j);
        ushort4 v1 = *(const ushort4*)(hw + (size_t)e1.x * DIM + j);
        a0 = fmaf(bf2f(v0.x), w0, a0); a1 = fmaf(bf2f(v0.y), w0, a1);
        a2 = fmaf(bf2f(v0.z), w0, a2); a3 = fmaf(bf2f(v0.w), w0, a3);
        a0 = fmaf(bf2f(v1.x), w1, a0); a1 = fmaf(bf2f(v1.y), w1, a1);
        a2 = fmaf(bf2f(v1.z), w1, a2); a3 = fmaf(bf2f(v1.w), w1, a3);
    }
    if (p < pe) {
        int2 e = epack[p];
        float w = __builtin_bit_cast(float, e.y);
        ushort4 v = *(const ushort4*)(hw + (size_t)e.x * DIM + j);
        a0 = fmaf(bf2f(v.x), w, a0); a1 = fmaf(bf2f(v.y), w, a1);
        a2 = fmaf(bf2f(v.z), w, a2); a3 = fmaf(bf2f(v.w), w, a3);
    }

    float4 b = *(const float4*)(bias + j);
    a0 += b.x; a1 += b.y; a2 += b.z; a3 += b.w;

    if (OUT_BF16) {
        unsigned short* out = (unsigned short*)out_;
        ushort4 o;
        o.x = f2bf(a0); o.y = f2bf(a1); o.z = f2bf(a2); o.w = f2bf(a3);
        *(ushort4*)(out + (size_t)node * DIM + j) = o;
    } else {
        float* out = (float*)out_;
        *(float4*)(out + (size_t)node * DIM + j) = make_float4(a0, a1, a2, a3);
    }
}

// ---------------- BN column stats over bf16 h1 ----------------

__global__ __launch_bounds__(256) void stats_kernel(const unsigned short* __restrict__ h,
                                                    float* __restrict__ stat, int n)
{
    const int tid = threadIdx.x;
    const int j2 = (tid & 63) * 2;
    const int ty = tid >> 6;                  // 0..3
    float s0 = 0.f, s1 = 0.f, q0 = 0.f, q1 = 0.f;
    for (int i = blockIdx.x * 4 + ty; i < n; i += gridDim.x * 4) {
        ushort2 v = *(const ushort2*)(h + (size_t)i * DIM + j2);
        float a = bf2f(v.x), b = bf2f(v.y);
        s0 += a; s1 += b; q0 += a * a; q1 += b * b;
    }
    __shared__ float ls[4][256];
    ls[0][tid] = s0; ls[1][tid] = s1; ls[2][tid] = q0; ls[3][tid] = q1;
    __syncthreads();
    if (tid < 64) {
        float r0 = ls[0][tid] + ls[0][tid + 64] + ls[0][tid + 128] + ls[0][tid + 192];
        float r1 = ls[1][tid] + ls[1][tid + 64] + ls[1][tid + 128] + ls[1][tid + 192];
        float r2 = ls[2][tid] + ls[2][tid + 64] + ls[2][tid + 128] + ls[2][tid + 192];
        float r3 = ls[3][tid] + ls[3][tid + 64] + ls[3][tid + 128] + ls[3][tid + 192];
        atomicAdd(&stat[j2],           r0);
        atomicAdd(&stat[j2 + 1],       r1);
        atomicAdd(&stat[DIM + j2],     r2);
        atomicAdd(&stat[DIM + j2 + 1], r3);
    }
}

__global__ void bn_finalize_kernel(const float* __restrict__ stat, float* __restrict__ mi, int n) {
    int j = threadIdx.x;
    if (j < DIM) {
        float mean = stat[j] / (float)n;
        float var  = stat[DIM + j] / (float)n - mean * mean;
        mi[j]       = mean;
        mi[DIM + j] = rsqrtf(var + BN_EPS);
    }
}

// ---------------- launch ----------------

extern "C" void kernel_launch(void* const* d_in, const int* in_sizes, int n_in,
                              void* d_out, int out_size, void* d_ws, size_t ws_size,
                              hipStream_t stream)
{
    const float* x      = (const float*)d_in[0];
    const int*   ei     = (const int*)  d_in[1];
    const float* W1     = (const float*)d_in[2];
    const float* b1     = (const float*)d_in[3];
    const float* gamma1 = (const float*)d_in[4];
    const float* beta1  = (const float*)d_in[5];
    const float* W2     = (const float*)d_in[6];
    const float* b2     = (const float*)d_in[7];
    float* out = (float*)d_out;

    const int N = in_sizes[0] / DIM;   // 100000
    const int E = in_sizes[1] / 2;     // 600000
    const int* row = ei;
    const int* col = ei + E;

    const int NB = (N + 1023) / 1024;

    // Workspace layout (~57 MB), 8B-alignment-safe ordering:
    unsigned short* hw    = (unsigned short*)d_ws;        // N*128 bf16
    unsigned short* h1    = hw + (size_t)N * DIM;         // N*128 bf16
    int2*  epack  = (int2*)(h1 + (size_t)N * DIM);        // E (8B each)
    unsigned short* wfrag = (unsigned short*)(epack + E); // 2*16384 bf16
    float* dis    = (float*)(wfrag + 2 * 16384);          // N
    int*   deg    = (int*)(dis + N);                      // N
    int*   cursor = deg + N;                              // N
    int*   rowptr = cursor + N;                           // N+1
    int*   aux    = rowptr + N + 1;                       // 128
    float* stat   = (float*)(aux + 128);                  // 256
    float* mi     = stat + 256;                           // 256

    hipMemsetAsync(deg,    0, (size_t)N * sizeof(int), stream);
    hipMemsetAsync(cursor, 0, (size_t)N * sizeof(int), stream);
    hipMemsetAsync(stat,   0, 256 * sizeof(float), stream);

    // Graph structure + W conversion
    deg_kernel<<<(E + 255) / 256, 256, 0, stream>>>(row, deg, E);
    dis_kernel<<<(N + 255) / 256, 256, 0, stream>>>(deg, dis, N);
    scan_block_kernel<<<NB, 256, 0, stream>>>(deg, rowptr, aux, N);
    scan_aux_kernel<<<1, 1, 0, stream>>>(aux, NB, rowptr, N, E);
    add_offsets_kernel<<<(N + 255) / 256, 256, 0, stream>>>(rowptr, aux, N);
    scatter_kernel<<<(E + 255) / 256, 256, 0, stream>>>(row, col, dis, rowptr, cursor,
                                                        epack, E);
    convert_w_kernel<<<16, 256, 0, stream>>>(W1, W2, wfrag);

    // Layer 1: hw = bf16(x @ W1) ; h1 = bf16(agg(hw)+self+b1) ; BN stats over h1
    gemm_mfma_f32_kernel<<<(N + 63) / 64, 256, 0, stream>>>(x, wfrag, hw, N);
    agg_csr_kernel<true><<<(N + 7) / 8, 256, 0, stream>>>(hw, dis, rowptr, epack, b1, h1, N);
    stats_kernel<<<512, 256, 0, stream>>>(h1, stat, N);
    bn_finalize_kernel<<<1, DIM, 0, stream>>>(stat, mi, N);

    // Layer 2: hw = bf16(relu(BN(h1)) @ W2) ; out = agg(hw)+self+b2 (fp32)
    gemm_mfma_bn_kernel<<<(N + 63) / 64, 256, 0, stream>>>(h1, wfrag + 16384, hw, N,
                                                           mi, mi + DIM, gamma1, beta1);
    agg_csr_kernel<false><<<(N + 7) / 8, 256, 0, stream>>>(hw, dis, rowptr, epack, b2, out, N);
}

// Round 5
// 315.812 us; speedup vs baseline: 2.7800x; 1.0965x over previous
//
#include <hip/hip_runtime.h>

#define DIM 128
#define BN_EPS 1e-5f

typedef short short8 __attribute__((ext_vector_type(8)));   // 8 bf16 bit patterns
typedef float floatx4 __attribute__((ext_vector_type(4)));

__device__ __forceinline__ unsigned short f2bf(float f) {
    unsigned int u = __builtin_bit_cast(unsigned int, f);
    u += 0x7FFFu + ((u >> 16) & 1u);          // RNE (inputs are finite)
    return (unsigned short)(u >> 16);
}
__device__ __forceinline__ float bf2f(unsigned short h) {
    return __builtin_bit_cast(float, (unsigned int)h << 16);
}

// ---------------- degree / norm ----------------

__global__ void deg_kernel(const int* __restrict__ row, int* __restrict__ deg, int E) {
    int e = blockIdx.x * blockDim.x + threadIdx.x;
    if (e < E) atomicAdd(&deg[row[e]], 1);
}

__global__ void dis_kernel(const int* __restrict__ deg, float* __restrict__ dis, int n) {
    int i = blockIdx.x * blockDim.x + threadIdx.x;
    if (i < n) dis[i] = rsqrtf((float)(deg[i] + 1));  // +1 self-loop; always > 0
}

// ---------------- exclusive scan over deg -> rowptr ----------------

__global__ __launch_bounds__(256) void scan_block_kernel(const int* __restrict__ deg,
                                                         int* __restrict__ rowptr,
                                                         int* __restrict__ aux, int n) {
    __shared__ int ls[256];
    const int base = blockIdx.x * 1024;
    const int t = threadIdx.x;
    int v[4]; int s = 0;
    #pragma unroll
    for (int k = 0; k < 4; ++k) {
        int i = base + t * 4 + k;
        v[k] = (i < n) ? deg[i] : 0;
        s += v[k];
    }
    ls[t] = s;
    __syncthreads();
    for (int off = 1; off < 256; off <<= 1) {
        int x = (t >= off) ? ls[t - off] : 0;
        __syncthreads();
        ls[t] += x;
        __syncthreads();
    }
    int excl = ls[t] - s;
    if (t == 255) aux[blockIdx.x] = ls[255];
    #pragma unroll
    for (int k = 0; k < 4; ++k) {
        int i = base + t * 4 + k;
        if (i < n) rowptr[i] = excl;
        excl += v[k];
    }
}

__global__ void scan_aux_kernel(int* __restrict__ aux, int nb, int* __restrict__ rowptr, int n, int E) {
    int s = 0;
    for (int i = 0; i < nb; ++i) { int v = aux[i]; aux[i] = s; s += v; }
    rowptr[n] = E;
}

__global__ void add_offsets_kernel(int* __restrict__ rowptr, const int* __restrict__ aux, int n) {
    int i = blockIdx.x * blockDim.x + threadIdx.x;
    if (i < n) rowptr[i] += aux[i >> 10];
}

// ---------------- scatter edges into CSR buckets: one 8B (col, norm) write ----

__global__ void scatter_kernel(const int* __restrict__ row, const int* __restrict__ col,
                               const float* __restrict__ dis, const int* __restrict__ rowptr,
                               int* __restrict__ cursor, int2* __restrict__ epack, int E) {
    int e = blockIdx.x * blockDim.x + threadIdx.x;
    if (e >= E) return;
    int r = row[e], c = col[e];
    int pos = rowptr[r] + atomicAdd(&cursor[r], 1);
    float nrm = dis[r] * dis[c];
    epack[pos] = make_int2(c, __builtin_bit_cast(int, nrm));
}

// ---------------- W -> bf16 B-fragment order ----------------
// wfrag[((kt*8+nt)*64 + lane)*8 + j] = W[kt*32 + (lane>>4)*8 + j][nt*16 + (lane&15)]

__global__ void convert_w_kernel(const float* __restrict__ W1, const float* __restrict__ W2,
                                 unsigned short* __restrict__ wfrag) {
    int s = blockIdx.x * blockDim.x + threadIdx.x;   // 0..4095
    if (s >= 4096) return;
    int m  = s >> 11;
    int s2 = s & 2047;
    int kt = s2 >> 9;
    int nt = (s2 >> 6) & 7;
    int l  = s2 & 63;
    const float* W = m ? W2 : W1;
    unsigned short* o = wfrag + (size_t)m * 16384 + (size_t)s2 * 8;
    int k0 = kt * 32 + (l >> 4) * 8;
    int n0 = nt * 16 + (l & 15);
    #pragma unroll
    for (int j = 0; j < 8; ++j) o[j] = f2bf(W[(k0 + j) * DIM + n0]);
}

// ---------------- MFMA GEMM, fp32 A input (layer 1, no BN) ----------------

__global__ __launch_bounds__(256) void gemm_mfma_f32_kernel(
    const float* __restrict__ A, const unsigned short* __restrict__ wfrag,
    unsigned short* __restrict__ C, int n)
{
    __shared__ unsigned short sA[64][136];
    const int tid  = threadIdx.x;
    const int row0 = blockIdx.x * 64;

    #pragma unroll
    for (int l = 0; l < 8; ++l) {
        int idx = tid + l * 256;
        int r   = idx >> 5;
        int c4  = (idx & 31) * 4;
        float4 v;
        if (row0 + r < n) v = *(const float4*)(A + (size_t)(row0 + r) * DIM + c4);
        else              v = make_float4(0.f, 0.f, 0.f, 0.f);
        unsigned int lo = (unsigned int)f2bf(v.x) | ((unsigned int)f2bf(v.y) << 16);
        unsigned int hi = (unsigned int)f2bf(v.z) | ((unsigned int)f2bf(v.w) << 16);
        *(uint2*)(&sA[r][c4]) = make_uint2(lo, hi);
    }
    __syncthreads();

    const int wave = tid >> 6;
    const int lane = tid & 63;
    const int m    = lane & 15;
    const int quad = lane >> 4;
    const int rowA = wave * 16 + m;

    short8 af[4];
    #pragma unroll
    for (int kt = 0; kt < 4; ++kt)
        af[kt] = *(const short8*)(&sA[rowA][kt * 32 + quad * 8]);

    floatx4 acc[8];
    #pragma unroll
    for (int nt = 0; nt < 8; ++nt) acc[nt] = (floatx4){0.f, 0.f, 0.f, 0.f};

    #pragma unroll
    for (int nt = 0; nt < 8; ++nt)
        #pragma unroll
        for (int kt = 0; kt < 4; ++kt) {
            short8 bfr = *(const short8*)(wfrag + ((size_t)(kt * 8 + nt) * 64 + lane) * 8);
            acc[nt] = __builtin_amdgcn_mfma_f32_16x16x32_bf16(af[kt], bfr, acc[nt], 0, 0, 0);
        }

    #pragma unroll
    for (int nt = 0; nt < 8; ++nt)
        #pragma unroll
        for (int r = 0; r < 4; ++r) {
            int rr = row0 + wave * 16 + quad * 4 + r;
            if (rr < n) C[(size_t)rr * DIM + nt * 16 + m] = f2bf(acc[nt][r]);
        }
}

// ---------------- MFMA GEMM, bf16 A input + fused BN/ReLU (layer 2) ----------------

__global__ __launch_bounds__(256) void gemm_mfma_bn_kernel(
    const unsigned short* __restrict__ A, const unsigned short* __restrict__ wfrag,
    unsigned short* __restrict__ C, int n,
    const float* __restrict__ mean, const float* __restrict__ istd,
    const float* __restrict__ gamma, const float* __restrict__ beta)
{
    __shared__ unsigned short sA[64][136];
    const int tid  = threadIdx.x;
    const int row0 = blockIdx.x * 64;

    #pragma unroll
    for (int l = 0; l < 4; ++l) {
        int idx = tid + l * 256;          // 0..1023, 16B chunks
        int r   = idx >> 4;
        int c8  = (idx & 15) * 8;
        uint4 u = make_uint4(0, 0, 0, 0);
        if (row0 + r < n) u = *(const uint4*)(A + (size_t)(row0 + r) * DIM + c8);
        float f[8] = { bf2f((unsigned short)(u.x & 0xffff)), bf2f((unsigned short)(u.x >> 16)),
                       bf2f((unsigned short)(u.y & 0xffff)), bf2f((unsigned short)(u.y >> 16)),
                       bf2f((unsigned short)(u.z & 0xffff)), bf2f((unsigned short)(u.z >> 16)),
                       bf2f((unsigned short)(u.w & 0xffff)), bf2f((unsigned short)(u.w >> 16)) };
        #pragma unroll
        for (int k = 0; k < 8; ++k) {
            int c = c8 + k;
            f[k] = fmaxf(fmaf(gamma[c] * (f[k] - mean[c]), istd[c], beta[c]), 0.f);
        }
        uint4 o;
        o.x = (unsigned int)f2bf(f[0]) | ((unsigned int)f2bf(f[1]) << 16);
        o.y = (unsigned int)f2bf(f[2]) | ((unsigned int)f2bf(f[3]) << 16);
        o.z = (unsigned int)f2bf(f[4]) | ((unsigned int)f2bf(f[5]) << 16);
        o.w = (unsigned int)f2bf(f[6]) | ((unsigned int)f2bf(f[7]) << 16);
        *(uint4*)(&sA[r][c8]) = o;
    }
    __syncthreads();

    const int wave = tid >> 6;
    const int lane = tid & 63;
    const int m    = lane & 15;
    const int quad = lane >> 4;
    const int rowA = wave * 16 + m;

    short8 af[4];
    #pragma unroll
    for (int kt = 0; kt < 4; ++kt)
        af[kt] = *(const short8*)(&sA[rowA][kt * 32 + quad * 8]);

    floatx4 acc[8];
    #pragma unroll
    for (int nt = 0; nt < 8; ++nt) acc[nt] = (floatx4){0.f, 0.f, 0.f, 0.f};

    #pragma unroll
    for (int nt = 0; nt < 8; ++nt)
        #pragma unroll
        for (int kt = 0; kt < 4; ++kt) {
            short8 bfr = *(const short8*)(wfrag + ((size_t)(kt * 8 + nt) * 64 + lane) * 8);
            acc[nt] = __builtin_amdgcn_mfma_f32_16x16x32_bf16(af[kt], bfr, acc[nt], 0, 0, 0);
        }

    #pragma unroll
    for (int nt = 0; nt < 8; ++nt)
        #pragma unroll
        for (int r = 0; r < 4; ++r) {
            int rr = row0 + wave * 16 + quad * 4 + r;
            if (rr < n) C[(size_t)rr * DIM + nt * 16 + m] = f2bf(acc[nt][r]);
        }
}

// ---------------- CSR aggregation: 16 lanes/node, 8 ch/lane (16 B gathers) ----------------
// out[i] = sum_e hw[col_e]*norm_e + hw[i]*dis_i^2 + bias ; fp32 accumulate.
// 2-edge unroll -> 2x16 B gathers in flight per lane.

template <bool OUT_BF16>
__global__ __launch_bounds__(256) void agg_csr_kernel(
    const unsigned short* __restrict__ hw, const float* __restrict__ dis,
    const int* __restrict__ rowptr, const int2* __restrict__ epack,
    const float* __restrict__ bias, void* __restrict__ out_, int n)
{
    const int sub  = threadIdx.x >> 4;        // 0..15 node slot in block
    const int l    = threadIdx.x & 15;
    const int node = blockIdx.x * 16 + sub;
    if (node >= n) return;
    const int j = l * 8;

    float acc[8];
    {
        const float d = dis[node];
        const float dd = d * d;
        uint4 u = *(const uint4*)(hw + (size_t)node * DIM + j);
        unsigned int uu[4] = {u.x, u.y, u.z, u.w};
        #pragma unroll
        for (int k = 0; k < 4; ++k) {
            acc[2*k]   = bf2f((unsigned short)(uu[k] & 0xffff)) * dd;
            acc[2*k+1] = bf2f((unsigned short)(uu[k] >> 16))    * dd;
        }
    }

    int p  = rowptr[node];
    const int pe = rowptr[node + 1];
    for (; p + 1 < pe; p += 2) {
        int2 e0 = epack[p], e1 = epack[p + 1];
        float w0 = __builtin_bit_cast(float, e0.y);
        float w1 = __builtin_bit_cast(float, e1.y);
        uint4 u0 = *(const uint4*)(hw + (size_t)e0.x * DIM + j);
        uint4 u1 = *(const uint4*)(hw + (size_t)e1.x * DIM + j);
        unsigned int a[4] = {u0.x, u0.y, u0.z, u0.w};
        unsigned int b[4] = {u1.x, u1.y, u1.z, u1.w};
        #pragma unroll
        for (int k = 0; k < 4; ++k) {
            acc[2*k]   = fmaf(bf2f((unsigned short)(a[k] & 0xffff)), w0, acc[2*k]);
            acc[2*k+1] = fmaf(bf2f((unsigned short)(a[k] >> 16)),    w0, acc[2*k+1]);
            acc[2*k]   = fmaf(bf2f((unsigned short)(b[k] & 0xffff)), w1, acc[2*k]);
            acc[2*k+1] = fmaf(bf2f((unsigned short)(b[k] >> 16)),    w1, acc[2*k+1]);
        }
    }
    if (p < pe) {
        int2 e = epack[p];
        float w = __builtin_bit_cast(float, e.y);
        uint4 u = *(const uint4*)(hw + (size_t)e.x * DIM + j);
        unsigned int a[4] = {u.x, u.y, u.z, u.w};
        #pragma unroll
        for (int k = 0; k < 4; ++k) {
            acc[2*k]   = fmaf(bf2f((unsigned short)(a[k] & 0xffff)), w, acc[2*k]);
            acc[2*k+1] = fmaf(bf2f((unsigned short)(a[k] >> 16)),    w, acc[2*k+1]);
        }
    }

    float4 b0 = *(const float4*)(bias + j);
    float4 b1 = *(const float4*)(bias + j + 4);
    acc[0] += b0.x; acc[1] += b0.y; acc[2] += b0.z; acc[3] += b0.w;
    acc[4] += b1.x; acc[5] += b1.y; acc[6] += b1.z; acc[7] += b1.w;

    if (OUT_BF16) {
        unsigned short* out = (unsigned short*)out_;
        uint4 o;
        o.x = (unsigned int)f2bf(acc[0]) | ((unsigned int)f2bf(acc[1]) << 16);
        o.y = (unsigned int)f2bf(acc[2]) | ((unsigned int)f2bf(acc[3]) << 16);
        o.z = (unsigned int)f2bf(acc[4]) | ((unsigned int)f2bf(acc[5]) << 16);
        o.w = (unsigned int)f2bf(acc[6]) | ((unsigned int)f2bf(acc[7]) << 16);
        *(uint4*)(out + (size_t)node * DIM + j) = o;
    } else {
        float* out = (float*)out_;
        *(float4*)(out + (size_t)node * DIM + j)     = make_float4(acc[0], acc[1], acc[2], acc[3]);
        *(float4*)(out + (size_t)node * DIM + j + 4) = make_float4(acc[4], acc[5], acc[6], acc[7]);
    }
}

// ---------------- BN column stats over bf16 h1 (16 B loads, 2x unroll) ----------------

__global__ __launch_bounds__(256) void stats_kernel(const unsigned short* __restrict__ h,
                                                    float* __restrict__ stat, int n)
{
    const int tid = threadIdx.x;
    const int cg  = tid & 15;       // channel group: channels cg*8..cg*8+7
    const int rg  = tid >> 4;       // row slot 0..15
    float s[8], q[8];
    #pragma unroll
    for (int k = 0; k < 8; ++k) { s[k] = 0.f; q[k] = 0.f; }

    const int stride = gridDim.x * 16;
    for (int i = blockIdx.x * 16 + rg; i < n; i += 2 * stride) {
        uint4 u0 = *(const uint4*)(h + (size_t)i * DIM + cg * 8);
        int i1 = i + stride;
        uint4 u1 = (i1 < n) ? *(const uint4*)(h + (size_t)i1 * DIM + cg * 8)
                            : make_uint4(0, 0, 0, 0);
        unsigned int a[4] = {u0.x, u0.y, u0.z, u0.w};
        unsigned int b[4] = {u1.x, u1.y, u1.z, u1.w};
        #pragma unroll
        for (int k = 0; k < 4; ++k) {
            float a0 = bf2f((unsigned short)(a[k] & 0xffff));
            float a1 = bf2f((unsigned short)(a[k] >> 16));
            float c0 = bf2f((unsigned short)(b[k] & 0xffff));
            float c1 = bf2f((unsigned short)(b[k] >> 16));
            s[2*k]   += a0 + c0;
            s[2*k+1] += a1 + c1;
            q[2*k]   = fmaf(a0, a0, fmaf(c0, c0, q[2*k]));
            q[2*k+1] = fmaf(a1, a1, fmaf(c1, c1, q[2*k+1]));
        }
    }

    __shared__ float red[16][128];
    #pragma unroll
    for (int k = 0; k < 8; ++k) red[rg][cg * 8 + k] = s[k];
    __syncthreads();
    if (tid < 128) {
        float t = 0.f;
        #pragma unroll
        for (int r = 0; r < 16; ++r) t += red[r][tid];
        atomicAdd(&stat[tid], t);
    }
    __syncthreads();
    #pragma unroll
    for (int k = 0; k < 8; ++k) red[rg][cg * 8 + k] = q[k];
    __syncthreads();
    if (tid < 128) {
        float t = 0.f;
        #pragma unroll
        for (int r = 0; r < 16; ++r) t += red[r][tid];
        atomicAdd(&stat[DIM + tid], t);
    }
}

__global__ void bn_finalize_kernel(const float* __restrict__ stat, float* __restrict__ mi, int n) {
    int j = threadIdx.x;
    if (j < DIM) {
        float mean = stat[j] / (float)n;
        float var  = stat[DIM + j] / (float)n - mean * mean;
        mi[j]       = mean;
        mi[DIM + j] = rsqrtf(var + BN_EPS);
    }
}

// ---------------- launch ----------------

extern "C" void kernel_launch(void* const* d_in, const int* in_sizes, int n_in,
                              void* d_out, int out_size, void* d_ws, size_t ws_size,
                              hipStream_t stream)
{
    const float* x      = (const float*)d_in[0];
    const int*   ei     = (const int*)  d_in[1];
    const float* W1     = (const float*)d_in[2];
    const float* b1     = (const float*)d_in[3];
    const float* gamma1 = (const float*)d_in[4];
    const float* beta1  = (const float*)d_in[5];
    const float* W2     = (const float*)d_in[6];
    const float* b2     = (const float*)d_in[7];
    float* out = (float*)d_out;

    const int N = in_sizes[0] / DIM;   // 100000
    const int E = in_sizes[1] / 2;     // 600000
    const int* row = ei;
    const int* col = ei + E;

    const int NB = (N + 1023) / 1024;

    // Workspace layout (~57 MB), 8B-alignment-safe ordering:
    unsigned short* hw    = (unsigned short*)d_ws;        // N*128 bf16
    unsigned short* h1    = hw + (size_t)N * DIM;         // N*128 bf16
    int2*  epack  = (int2*)(h1 + (size_t)N * DIM);        // E (8B each)
    unsigned short* wfrag = (unsigned short*)(epack + E); // 2*16384 bf16
    float* dis    = (float*)(wfrag + 2 * 16384);          // N
    int*   deg    = (int*)(dis + N);                      // N
    int*   cursor = deg + N;                              // N
    int*   rowptr = cursor + N;                           // N+1
    int*   aux    = rowptr + N + 1;                       // 128
    float* stat   = (float*)(aux + 128);                  // 256
    float* mi     = stat + 256;                           // 256

    hipMemsetAsync(deg,    0, (size_t)N * sizeof(int), stream);
    hipMemsetAsync(cursor, 0, (size_t)N * sizeof(int), stream);
    hipMemsetAsync(stat,   0, 256 * sizeof(float), stream);

    // Graph structure + W conversion
    deg_kernel<<<(E + 255) / 256, 256, 0, stream>>>(row, deg, E);
    dis_kernel<<<(N + 255) / 256, 256, 0, stream>>>(deg, dis, N);
    scan_block_kernel<<<NB, 256, 0, stream>>>(deg, rowptr, aux, N);
    scan_aux_kernel<<<1, 1, 0, stream>>>(aux, NB, rowptr, N, E);
    add_offsets_kernel<<<(N + 255) / 256, 256, 0, stream>>>(rowptr, aux, N);
    scatter_kernel<<<(E + 255) / 256, 256, 0, stream>>>(row, col, dis, rowptr, cursor,
                                                        epack, E);
    convert_w_kernel<<<16, 256, 0, stream>>>(W1, W2, wfrag);

    // Layer 1: hw = bf16(x @ W1) ; h1 = bf16(agg(hw)+self+b1) ; BN stats over h1
    gemm_mfma_f32_kernel<<<(N + 63) / 64, 256, 0, stream>>>(x, wfrag, hw, N);
    agg_csr_kernel<true><<<(N + 15) / 16, 256, 0, stream>>>(hw, dis, rowptr, epack, b1, h1, N);
    stats_kernel<<<512, 256, 0, stream>>>(h1, stat, N);
    bn_finalize_kernel<<<1, DIM, 0, stream>>>(stat, mi, N);

    // Layer 2: hw = bf16(relu(BN(h1)) @ W2) ; out = agg(hw)+self+b2 (fp32)
    gemm_mfma_bn_kernel<<<(N + 63) / 64, 256, 0, stream>>>(h1, wfrag + 16384, hw, N,
                                                           mi, mi + DIM, gamma1, beta1);
    agg_csr_kernel<false><<<(N + 15) / 16, 256, 0, stream>>>(hw, dis, rowptr, epack, b2, out, N);
}